// Round 12
// baseline (179.223 us; speedup 1.0000x reference)
//
#include <hip/hip_runtime.h>
#include <hip/hip_bf16.h>

#define LRELU_ALPHA 0.2f

constexpr int N   = 8192;
constexpr int FIN = 512;
constexpr int F   = 128;
constexpr int BRW = 16;          // rows per wave (attn)
constexpr int BR  = 64;          // rows per block (attn, 4 waves)

typedef __attribute__((ext_vector_type(4))) float f32x4;
typedef __attribute__((ext_vector_type(8))) short s16x8;
typedef unsigned long long u64;

static __device__ __forceinline__ short f2bf(float x) {
  unsigned u = __float_as_uint(x);
  return (short)((u + 0x7fffu + ((u >> 16) & 1u)) >> 16);   // RNE bf16
}

// ---------------------------------------------------------------------------
// K1 "producer", block-specialized 4:1 (unchanged from R11).
//  - mask blocks (1024): ballot-compress adj -> bitmask[8192][128] u64.
//  - wh blocks (256): Bpack = (h@w)^T bf16 fragment-packed; Wh1; Wh2.
// ---------------------------------------------------------------------------
__global__ __launch_bounds__(512) void k_prod(
    const float* __restrict__ h, const float* __restrict__ w,
    const float* __restrict__ a, const int* __restrict__ adj,
    short* __restrict__ Bpack, float* __restrict__ Wh1,
    float* __restrict__ Wh2, u64* __restrict__ mask) {
  const int bx = blockIdx.x;
  if ((bx % 5) != 4) {
    const int mask_id = (bx / 5) * 4 + (bx % 5);        // 0..1023
    const int l   = threadIdx.x & 63;
    const int row = mask_id * 8 + (threadIdx.x >> 6);
    const int* __restrict__ rp = adj + (size_t)row * N;
    u64* __restrict__ mp = mask + (size_t)row * (N / 64);
    for (int it = 0; it < N / 512; ++it) {              // 16 x 512 j
      int v[8];
#pragma unroll
      for (int k = 0; k < 8; ++k) v[k] = rp[it * 512 + l + k * 64];
      u64 m[8];
#pragma unroll
      for (int k = 0; k < 8; ++k) m[k] = __ballot(v[k] > 0);
      if (l == 0) {
        ulonglong2 s0 = {m[0], m[1]}, s1 = {m[2], m[3]};
        ulonglong2 s2 = {m[4], m[5]}, s3 = {m[6], m[7]};
        *(ulonglong2*)(mp + it * 8)     = s0;
        *(ulonglong2*)(mp + it * 8 + 2) = s1;
        *(ulonglong2*)(mp + it * 8 + 4) = s2;
        *(ulonglong2*)(mp + it * 8 + 6) = s3;
      }
    }
    return;
  }
  __shared__ float hl[32][68];
  __shared__ float wl[64][128];
  const int t    = threadIdx.x;
  const int i0   = (bx / 5) * 32;
  const int col4 = (t & 31) * 4;
  const int rq   = t >> 5;              // 0..15 -> rows rq*2, rq*2+1
  float acc[2][4] = {};

  for (int k0 = 0; k0 < FIN; k0 += 64) {
    *(f32x4*)&hl[t >> 4][(t & 15) * 4] =
        *(const f32x4*)(h + (size_t)(i0 + (t >> 4)) * FIN + k0 + (t & 15) * 4);
#pragma unroll
    for (int j = 0; j < 4; ++j) {
      int c = t + 512 * j;
      int kr = c >> 5, f4 = (c & 31) * 4;
      *(f32x4*)&wl[kr][f4] = *(const f32x4*)(w + (size_t)(k0 + kr) * F + f4);
    }
    __syncthreads();
#pragma unroll 4
    for (int k4 = 0; k4 < 64; k4 += 4) {
      f32x4 wv[4];
#pragma unroll
      for (int u = 0; u < 4; ++u) wv[u] = *(const f32x4*)&wl[k4 + u][col4];
#pragma unroll
      for (int ri = 0; ri < 2; ++ri) {
        f32x4 hv = *(const f32x4*)&hl[rq * 2 + ri][k4];
#pragma unroll
        for (int u = 0; u < 4; ++u) {
#pragma unroll
          for (int ci = 0; ci < 4; ++ci) acc[ri][ci] += hv[u] * wv[u][ci];
        }
      }
    }
    __syncthreads();
  }
  {
    const int kt    = i0 >> 5;
    const int kslot = rq >> 2;
    const int u     = (rq * 2) & 7;
#pragma unroll
    for (int ci = 0; ci < 4; ++ci) {
      int f = col4 + ci;
      int nb = f >> 4, c = f & 15;
      unsigned pk = (unsigned)(unsigned short)f2bf(acc[0][ci]) |
                    ((unsigned)(unsigned short)f2bf(acc[1][ci]) << 16);
      size_t idx = (size_t)(kt * 8 + nb) * 512 + (kslot * 16 + c) * 8 + u;
      *(unsigned*)(Bpack + idx) = pk;
    }
  }
  f32x4 av1 = *(const f32x4*)(a + col4);
  f32x4 av2 = *(const f32x4*)(a + F + col4);
  float s1[2], s2[2];
#pragma unroll
  for (int ri = 0; ri < 2; ++ri) {
    s1[ri] = acc[ri][0] * av1[0] + acc[ri][1] * av1[1] +
             acc[ri][2] * av1[2] + acc[ri][3] * av1[3];
    s2[ri] = acc[ri][0] * av2[0] + acc[ri][1] * av2[1] +
             acc[ri][2] * av2[2] + acc[ri][3] * av2[3];
  }
#pragma unroll
  for (int off = 1; off < 32; off <<= 1) {
#pragma unroll
    for (int ri = 0; ri < 2; ++ri) {
      s1[ri] += __shfl_xor(s1[ri], off);
      s2[ri] += __shfl_xor(s2[ri], off);
    }
  }
  if ((t & 31) == 0) {
#pragma unroll
    for (int ri = 0; ri < 2; ++ri) {
      Wh1[i0 + rq * 2 + ri] = s1[ri];
      Wh2[i0 + rq * 2 + ri] = s2[ri];
    }
  }
}

// ---------------------------------------------------------------------------
// K2: fused GAT attention partials. Same skeleton as R11 (no HBM / barriers /
// ballots in the loop) with a SHORTER phase critical path:
//  - P pack via v_cvt_pk_bf16_f32 (4 instrs, replaces 24-op manual RNE)
//  - row-sums via one extra MFMA against an all-ones B fragment (deletes the
//    8 lsum adds per phase and the epilogue shuffle reduction)
// ---------------------------------------------------------------------------
template <int KS>
__global__ __launch_bounds__(256) __attribute__((amdgpu_waves_per_eu(1, 4)))
void k_attn(
    const u64* __restrict__ mask, const float* __restrict__ Wh1v,
    const float* __restrict__ Wh2v, const short* __restrict__ Bpack,
    float* __restrict__ accP, float* __restrict__ lP) {
  constexpr int JW  = N / KS;
  constexpr int NTL = JW / 32;     // phases (32 for KS=8) -- even
  __shared__ float w2l[JW];

  const int t   = threadIdx.x;
  const int l   = t & 63;
  const int w   = t >> 6;
  const int r16 = l & 15;
  const int g8  = (l >> 4) * 8;
  const int i0  = blockIdx.x * BR;
  const int s   = blockIdx.y;

  const int row  = i0 + w * BRW + r16;
  const float w1 = Wh1v[row];
  const u64* __restrict__ mrow = mask + (size_t)row * (N / 64) + s * (JW / 64);
  const short* __restrict__ bq = Bpack + (size_t)s * NTL * 8 * 512 + l * 8;

  f32x4 acc[8] = {};
  f32x4 acc_l  = {};               // rowsum accumulator (MFMA-ones)
  const s16x8 ones = {(short)0x3F80, (short)0x3F80, (short)0x3F80,
                      (short)0x3F80, (short)0x3F80, (short)0x3F80,
                      (short)0x3F80, (short)0x3F80};   // bf16 1.0 x8
  s16x8 bfA[8], bfB[8];
  u64 mA, mB;

#define BF_LOAD(bf, tt)                                                      \
  _Pragma("unroll") for (int nb = 0; nb < 8; ++nb)                           \
      bf[nb] = *(const s16x8*)(bq + (size_t)((tt) * 8 + nb) * 512);

  auto scores8 = [&](unsigned mb, int tt, s16x8& af) {
    const f32x4 y0 = *(const f32x4*)&w2l[tt * 32 + g8];
    const f32x4 y1 = *(const f32x4*)&w2l[tt * 32 + g8 + 4];
    float p[8];
#pragma unroll
    for (int u = 0; u < 4; ++u) {
      float x = w1 + y0[u]; x = fmaxf(x, LRELU_ALPHA * x);
      p[u] = (mb >> u) & 1u ? __expf(x) : 0.f;
    }
#pragma unroll
    for (int u = 0; u < 4; ++u) {
      float x = w1 + y1[u]; x = fmaxf(x, LRELU_ALPHA * x);
      p[4 + u] = (mb >> (4 + u)) & 1u ? __expf(x) : 0.f;
    }
    union { unsigned u32[4]; s16x8 v; } pk;
    asm("v_cvt_pk_bf16_f32 %0, %1, %2" : "=v"(pk.u32[0]) : "v"(p[0]), "v"(p[1]));
    asm("v_cvt_pk_bf16_f32 %0, %1, %2" : "=v"(pk.u32[1]) : "v"(p[2]), "v"(p[3]));
    asm("v_cvt_pk_bf16_f32 %0, %1, %2" : "=v"(pk.u32[2]) : "v"(p[4]), "v"(p[5]));
    asm("v_cvt_pk_bf16_f32 %0, %1, %2" : "=v"(pk.u32[3]) : "v"(p[6]), "v"(p[7]));
    af = pk.v;
  };

  // ---- prologue: Wh2 -> LDS; bf(0); mask u64 for phases 0,1 ----
#pragma unroll
  for (int j4 = t; j4 < JW / 4; j4 += 256)
    *(f32x4*)&w2l[j4 * 4] = *(const f32x4*)(Wh2v + (size_t)s * JW + j4 * 4);
  BF_LOAD(bfA, 0)
  mA = mrow[0];
  __syncthreads();                 // one-time drain; regs stay valid

  for (int tt = 0; tt < NTL; tt += 2) {
    // ---- even phase tt: consume bfA + mA.lo; issue bfB(tt+1), m(tt+2) ----
    {
      BF_LOAD(bfB, tt + 1)                       // tt+1 < NTL (NTL even)
      if (tt + 2 < NTL) mB = mrow[tt / 2 + 1];
      s16x8 af;
      scores8((unsigned)(mA >> g8) & 0xffu, tt, af);
      acc_l = __builtin_amdgcn_mfma_f32_16x16x32_bf16(af, ones, acc_l, 0, 0, 0);
#pragma unroll
      for (int nb = 0; nb < 8; ++nb)
        acc[nb] = __builtin_amdgcn_mfma_f32_16x16x32_bf16(af, bfA[nb],
                                                          acc[nb], 0, 0, 0);
    }
    // ---- odd phase tt+1: consume bfB + mA.hi; issue bfA(tt+2) ----
    {
      if (tt + 2 < NTL) BF_LOAD(bfA, tt + 2)
      s16x8 af;
      scores8((unsigned)(mA >> (32 + g8)) & 0xffu, tt + 1, af);
      acc_l = __builtin_amdgcn_mfma_f32_16x16x32_bf16(af, ones, acc_l, 0, 0, 0);
#pragma unroll
      for (int nb = 0; nb < 8; ++nb)
        acc[nb] = __builtin_amdgcn_mfma_f32_16x16x32_bf16(af, bfB[nb],
                                                          acc[nb], 0, 0, 0);
      mA = mB;
    }
  }
#undef BF_LOAD

  // row-sums: every C column of the ones-MFMA holds the same value, so each
  // lane already has full rowsums for its 4 C-rows; lanes with r16==0 write.
  if (r16 == 0) {
#pragma unroll
    for (int rg = 0; rg < 4; ++rg)
      lP[(size_t)s * N + i0 + w * BRW + (l >> 4) * 4 + rg] = acc_l[rg];
  }
  // partial accumulator (C layout: row=(l>>4)*4+rg, col=l&15)
  float* op = accP + (size_t)s * N * F;
#pragma unroll
  for (int nb = 0; nb < 8; ++nb) {
#pragma unroll
    for (int rg = 0; rg < 4; ++rg) {
      int r = i0 + w * BRW + (l >> 4) * 4 + rg;
      op[(size_t)r * F + nb * 16 + r16] = acc[nb][rg];
    }
  }
}

// ---------------------------------------------------------------------------
// K3: combine partials: out = elu( (sum_s accP) / (sum_s lP) )
// ---------------------------------------------------------------------------
template <int KS>
__global__ __launch_bounds__(256) void k_comb(
    const float* __restrict__ accP, const float* __restrict__ lP,
    float* __restrict__ out) {
  const int idx = blockIdx.x * 256 + threadIdx.x;  // one f32x4 per thread
  const int i   = idx >> 5;                        // row (F/4 = 32 per row)
  f32x4 v = {};
  float lt = 0.f;
#pragma unroll
  for (int s = 0; s < KS; ++s) {
    v += *(const f32x4*)(accP + (size_t)s * N * F + (size_t)idx * 4);
    lt += lP[(size_t)s * N + i];
  }
  f32x4 o;
#pragma unroll
  for (int u = 0; u < 4; ++u) {
    float x = v[u] / lt;
    o[u] = x > 0.f ? x : __expf(x) - 1.f;          // ELU
  }
  *(f32x4*)(out + (size_t)idx * 4) = o;
}

// ---------------------------------------------------------------------------
extern "C" void kernel_launch(void* const* d_in, const int* in_sizes, int n_in,
                              void* d_out, int out_size, void* d_ws, size_t ws_size,
                              hipStream_t stream) {
  const float* h   = (const float*)d_in[0];
  const int*   adj = (const int*)d_in[1];
  const float* w   = (const float*)d_in[2];
  const float* a   = (const float*)d_in[3];
  float* out = (float*)d_out;

  // ws: Bpack bf16 (2 MB) | Wh1 [N] | Wh2 [N] | mask [N][N/64] u64 (8 MB)
  //     | lP [KS][N] | accP [KS][N][F]
  char* ws = (char*)d_ws;
  short* Bpack = (short*)ws;
  float* Wh1 = (float*)(ws + (size_t)F * N * 2);
  float* Wh2 = Wh1 + N;
  u64*  mask = (u64*)(Wh2 + N);
  float* lP  = (float*)(mask + (size_t)N * (N / 64));

  const size_t fixed = (size_t)F * N * 2 + 2 * (size_t)N * 4 +
                       (size_t)N * (N / 64) * 8;
  const size_t need8 = fixed + 8 * (size_t)N * 4 + 8 * (size_t)N * F * 4;

  k_prod<<<1280, 512, 0, stream>>>(h, w, a, adj, Bpack, Wh1, Wh2, mask);
  if (ws_size >= need8) {
    constexpr int KS = 8;
    float* accP = lP + (size_t)KS * N;
    // MEASUREMENT: k_attn dispatched twice (idempotent pure stores) so this
    // round's total-time delta pins k_attn's duration exactly; the dup is
    // removed next round.
    k_attn<KS><<<dim3(N / BR, KS), 256, 0, stream>>>(mask, Wh1, Wh2, Bpack,
                                                     accP, lP);
    k_attn<KS><<<dim3(N / BR, KS), 256, 0, stream>>>(mask, Wh1, Wh2, Bpack,
                                                     accP, lP);
    k_comb<KS><<<(N * F / 4) / 256, 256, 0, stream>>>(accP, lP, out);
  } else {
    constexpr int KS = 4;
    float* accP = lP + (size_t)KS * N;
    k_attn<KS><<<dim3(N / BR, KS), 256, 0, stream>>>(mask, Wh1, Wh2, Bpack,
                                                     accP, lP);
    k_attn<KS><<<dim3(N / BR, KS), 256, 0, stream>>>(mask, Wh1, Wh2, Bpack,
                                                     accP, lP);
    k_comb<KS><<<(N * F / 4) / 256, 256, 0, stream>>>(accP, lP, out);
  }
}